// Round 1
// baseline (1136.162 us; speedup 1.0000x reference)
//
#include <hip/hip_runtime.h>
#include <hip/hip_bf16.h>

#define E_    8
#define T_    4096
#define D_    2048
#define HDIM  1024

typedef __bf16 bf16_t;
typedef __bf16 bf16x8 __attribute__((ext_vector_type(8)));
typedef __bf16 bf16x4 __attribute__((ext_vector_type(4)));
typedef float  floatx4 __attribute__((ext_vector_type(4)));

// ---------------- prep kernels ----------------

// fp32 -> bf16, 4 elements/thread (float4 load, 8B store)
__global__ void cvt_f32_bf16(const float* __restrict__ in, bf16_t* __restrict__ out, long n4) {
  long i = (long)blockIdx.x * blockDim.x + threadIdx.x;
  if (i >= n4) return;
  const float4 v = ((const float4*)in)[i];
  bf16x4 o;
  o[0] = (bf16_t)v.x; o[1] = (bf16_t)v.y; o[2] = (bf16_t)v.z; o[3] = (bf16_t)v.w;
  ((bf16x4*)out)[i] = o;
}

// in: R x C fp32 row-major (per expert), out: C x R bf16 row-major (per expert)
__global__ void transpose_cvt(const float* __restrict__ in, bf16_t* __restrict__ out,
                              int R, int C, long sIn, long sOut) {
  __shared__ float t[32][33];   // +1 pad: no bank conflicts
  const float* inE = in + (long)blockIdx.z * sIn;
  bf16_t* outE = out + (long)blockIdx.z * sOut;
  const int tx = threadIdx.x & 31;
  const int ty = threadIdx.x >> 5;     // 0..7
  const int c0 = blockIdx.x * 32;
  const int r0 = blockIdx.y * 32;
#pragma unroll
  for (int j = 0; j < 4; ++j) {
    int r = ty + j * 8;
    t[r][tx] = inE[(long)(r0 + r) * C + c0 + tx];
  }
  __syncthreads();
#pragma unroll
  for (int j = 0; j < 4; ++j) {
    int c = ty + j * 8;
    outE[(long)(c0 + c) * R + r0 + tx] = (bf16_t)t[tx][c];
  }
}

// ---------------- GEMM common ----------------

__device__ __forceinline__ void async_cp16(const bf16_t* g, bf16_t* l) {
  __builtin_amdgcn_global_load_lds(
      (const __attribute__((address_space(1))) unsigned int*)(g),
      (__attribute__((address_space(3))) unsigned int*)(l), 16, 0, 0);
}

// raw barrier: NO implicit vmcnt drain (that drain is the m97 ~900TF ceiling).
// sched_barrier(0) fences code motion on both sides so ds_reads can't hoist
// above the barrier that guarantees staged data has landed.
__device__ __forceinline__ void phase_barrier() {
  __builtin_amdgcn_sched_barrier(0);
  __builtin_amdgcn_s_barrier();
  __builtin_amdgcn_sched_barrier(0);
}

#define MFMA_BF16 __builtin_amdgcn_mfma_f32_16x16x32_bf16

// ---------------- GEMM1: h = silu(X@W1) * (X@W3), fused ----------------
// Block tile: 256(M) x 128(N), BK=32, 4-slot LDS ring, 2 phases/K-tile.
// X: [T][K=2048] bf16; W1t/W3t: [N=1024][K] bf16; Hout: [T][1024] bf16.
__global__ __launch_bounds__(512, 2) void gemm1_silu(
    const bf16_t* __restrict__ X, const bf16_t* __restrict__ W1t,
    const bf16_t* __restrict__ W3t, bf16_t* __restrict__ Hout,
    long sx, long sw, long sh) {
  const int K  = D_;        // 2048
  const int NT = K / 32;    // 64 K-tiles
  const bf16_t* A  = X   + (long)blockIdx.z * sx;
  const bf16_t* B1 = W1t + (long)blockIdx.z * sw;
  const bf16_t* B3 = W3t + (long)blockIdx.z * sw;
  bf16_t* HO = Hout + (long)blockIdx.z * sh;

  const int m0 = blockIdx.y * 256;
  const int n0 = blockIdx.x * 128;

  __shared__ bf16_t As [4 * 256 * 32];   // 64 KB (slot = 8192 elems)
  __shared__ bf16_t B1s[4 * 128 * 32];   // 32 KB (slot = 4096 elems)
  __shared__ bf16_t B3s[4 * 128 * 32];   // 32 KB   -> 128 KB total

  const int tid  = threadIdx.x;
  const int lane = tid & 63;
  const int wave = tid >> 6;          // 0..7
  const int wm   = (wave >> 2) * 128; // 2 wave-rows
  const int wn   = (wave & 3) * 32;   // 4 wave-cols
  const int quad = lane >> 4;
  const int l16  = lane & 15;

  // staging geometry: 512 thr x 16B = 8KB/call; A tile 16KB = 2 calls, B tiles 8KB = 1 call
  const int srow = tid >> 2;          // 0..127
  const int scol = (tid & 3) * 8;     // bf16 elems

  const bf16_t* pa0 = A  + (long)(m0 + srow) * K + scol;
  const bf16_t* pa1 = A  + (long)(m0 + 128 + srow) * K + scol;
  const bf16_t* pb1 = B1 + (long)(n0 + srow) * K + scol;
  const bf16_t* pb3 = B3 + (long)(n0 + srow) * K + scol;
  bf16_t* la  = As  + tid * 8;
  bf16_t* lb1 = B1s + tid * 8;
  bf16_t* lb3 = B3s + tid * 8;

  auto stageA = [&](int kt, int slot) {
    async_cp16(pa0 + kt * 32, la + slot * 8192);
    async_cp16(pa1 + kt * 32, la + slot * 8192 + 4096);
  };
  auto stageB = [&](int kt, int slot) {
    async_cp16(pb1 + kt * 32, lb1 + slot * 4096);
    async_cp16(pb3 + kt * 32, lb3 + slot * 4096);
  };

  floatx4 acc1[8][2] = {};
  floatx4 acc3[8][2] = {};

  // prologue: K-tiles 0..2 -> slots 0..2 (12 loads in flight)
  stageA(0, 0); stageB(0, 0);
  stageA(1, 1); stageB(1, 1);
  stageA(2, 2); stageB(2, 2);

  for (int t = 0; t < NT; ++t) {
    const int c  = t & 3;
    const int s  = (t + 3) & 3;
    const int kp = (t + 3 < NT) ? (t + 3) : (NT - 1);

    // issue A of K-tile t+3 (slot s freed by end-barrier of iter t-1)
    stageA(kp, s);
    // outstanding: K_t(4)+K_{t+1}(4)+K_{t+2}(4)+K_{t+3}(2)=14 -> drain exactly K_t
    asm volatile("s_waitcnt vmcnt(10)" ::: "memory");
    phase_barrier();   // all waves' K_t slices landed -> slot c readable

    const bf16_t* Ab  = As  + c * 8192;
    const bf16_t* Bb1 = B1s + c * 4096;
    const bf16_t* Bb3 = B3s + c * 4096;

    bf16x8 af[8];
#pragma unroll
    for (int i = 0; i < 8; ++i)
      af[i] = *(const bf16x8*)(Ab + (wm + i * 16 + l16) * 32 + quad * 8);
    bf16x8 b1a = *(const bf16x8*)(Bb1 + (wn + l16) * 32 + quad * 8);
    bf16x8 b1b = *(const bf16x8*)(Bb1 + (wn + 16 + l16) * 32 + quad * 8);

    __builtin_amdgcn_s_setprio(1);
#pragma unroll
    for (int i = 0; i < 8; ++i) {
      acc1[i][0] = MFMA_BF16(af[i], b1a, acc1[i][0], 0, 0, 0);
      acc1[i][1] = MFMA_BF16(af[i], b1b, acc1[i][1], 0, 0, 0);
    }
    __builtin_amdgcn_s_setprio(0);
    phase_barrier();

    bf16x8 b3a = *(const bf16x8*)(Bb3 + (wn + l16) * 32 + quad * 8);
    bf16x8 b3b = *(const bf16x8*)(Bb3 + (wn + 16 + l16) * 32 + quad * 8);
    stageB(kp, s);     // B of K-tile t+3

    __builtin_amdgcn_s_setprio(1);
#pragma unroll
    for (int i = 0; i < 8; ++i) {
      acc3[i][0] = MFMA_BF16(af[i], b3a, acc3[i][0], 0, 0, 0);
      acc3[i][1] = MFMA_BF16(af[i], b3b, acc3[i][1], 0, 0, 0);
    }
    __builtin_amdgcn_s_setprio(0);
    phase_barrier();   // end-of-iter: frees slot s for iter t+1's stageA
  }

  // epilogue: silu(g)*u -> bf16. C/D layout: col=lane&15, row=quad*4+reg (m89)
#pragma unroll
  for (int i = 0; i < 8; ++i)
#pragma unroll
    for (int n = 0; n < 2; ++n) {
      const int col = n0 + wn + n * 16 + l16;
#pragma unroll
      for (int r = 0; r < 4; ++r) {
        const int row = m0 + wm + i * 16 + quad * 4 + r;
        float g = acc1[i][n][r];
        float u = acc3[i][n][r];
        float sv = g / (1.0f + __expf(-g));
        HO[(long)row * HDIM + col] = (bf16_t)(sv * u);
      }
    }
}

// ---------------- GEMM2: Out = H @ W2 ----------------
// Block tile: 256 x 256, BK=32, same 4-slot ring / 2-phase schedule.
// Hin: [T][K=1024] bf16; W2t: [N=2048][K] bf16; Out: [T][2048] fp32.
__global__ __launch_bounds__(512, 2) void gemm2(
    const bf16_t* __restrict__ Hin, const bf16_t* __restrict__ W2t,
    float* __restrict__ Out, long sh, long sw, long so) {
  const int K  = HDIM;      // 1024
  const int NT = K / 32;    // 32
  const bf16_t* A = Hin + (long)blockIdx.z * sh;
  const bf16_t* B = W2t + (long)blockIdx.z * sw;
  float* C = Out + (long)blockIdx.z * so;

  const int m0 = blockIdx.y * 256;
  const int n0 = blockIdx.x * 256;

  __shared__ bf16_t As[4 * 256 * 32];   // 64 KB
  __shared__ bf16_t Bs[4 * 256 * 32];   // 64 KB -> 128 KB total

  const int tid  = threadIdx.x;
  const int lane = tid & 63;
  const int wave = tid >> 6;
  const int wm   = (wave >> 2) * 128;
  const int wn   = (wave & 3) * 64;
  const int quad = lane >> 4;
  const int l16  = lane & 15;

  const int srow = tid >> 2;
  const int scol = (tid & 3) * 8;

  const bf16_t* pa0 = A + (long)(m0 + srow) * K + scol;
  const bf16_t* pa1 = A + (long)(m0 + 128 + srow) * K + scol;
  const bf16_t* pb0 = B + (long)(n0 + srow) * K + scol;
  const bf16_t* pb1 = B + (long)(n0 + 128 + srow) * K + scol;
  bf16_t* la = As + tid * 8;
  bf16_t* lb = Bs + tid * 8;

  auto stageA = [&](int kt, int slot) {
    async_cp16(pa0 + kt * 32, la + slot * 8192);
    async_cp16(pa1 + kt * 32, la + slot * 8192 + 4096);
  };
  auto stageB = [&](int kt, int slot) {
    async_cp16(pb0 + kt * 32, lb + slot * 8192);
    async_cp16(pb1 + kt * 32, lb + slot * 8192 + 4096);
  };

  floatx4 acc[8][4] = {};

  stageA(0, 0); stageB(0, 0);
  stageA(1, 1); stageB(1, 1);
  stageA(2, 2); stageB(2, 2);

  for (int t = 0; t < NT; ++t) {
    const int c  = t & 3;
    const int s  = (t + 3) & 3;
    const int kp = (t + 3 < NT) ? (t + 3) : (NT - 1);

    stageA(kp, s);
    asm volatile("s_waitcnt vmcnt(10)" ::: "memory");
    phase_barrier();

    const bf16_t* Ab = As + c * 8192;
    const bf16_t* Bb = Bs + c * 8192;

    bf16x8 af[8];
#pragma unroll
    for (int i = 0; i < 8; ++i)
      af[i] = *(const bf16x8*)(Ab + (wm + i * 16 + l16) * 32 + quad * 8);
    bf16x8 bf0 = *(const bf16x8*)(Bb + (wn + l16) * 32 + quad * 8);
    bf16x8 bf1 = *(const bf16x8*)(Bb + (wn + 16 + l16) * 32 + quad * 8);

    __builtin_amdgcn_s_setprio(1);
#pragma unroll
    for (int i = 0; i < 8; ++i) {
      acc[i][0] = MFMA_BF16(af[i], bf0, acc[i][0], 0, 0, 0);
      acc[i][1] = MFMA_BF16(af[i], bf1, acc[i][1], 0, 0, 0);
    }
    __builtin_amdgcn_s_setprio(0);
    phase_barrier();

    bf16x8 bf2 = *(const bf16x8*)(Bb + (wn + 32 + l16) * 32 + quad * 8);
    bf16x8 bf3 = *(const bf16x8*)(Bb + (wn + 48 + l16) * 32 + quad * 8);
    stageB(kp, s);

    __builtin_amdgcn_s_setprio(1);
#pragma unroll
    for (int i = 0; i < 8; ++i) {
      acc[i][2] = MFMA_BF16(af[i], bf2, acc[i][2], 0, 0, 0);
      acc[i][3] = MFMA_BF16(af[i], bf3, acc[i][3], 0, 0, 0);
    }
    __builtin_amdgcn_s_setprio(0);
    phase_barrier();
  }

#pragma unroll
  for (int i = 0; i < 8; ++i)
#pragma unroll
    for (int n = 0; n < 4; ++n) {
      const int col = n0 + wn + n * 16 + l16;
#pragma unroll
      for (int r = 0; r < 4; ++r) {
        const int row = m0 + wm + i * 16 + quad * 4 + r;
        C[(long)row * D_ + col] = acc[i][n][r];
      }
    }
}

// ---------------- launcher ----------------

extern "C" void kernel_launch(void* const* d_in, const int* in_sizes, int n_in,
                              void* d_out, int out_size, void* d_ws, size_t ws_size,
                              hipStream_t stream) {
  const float* x  = (const float*)d_in[0];
  const float* w1 = (const float*)d_in[1];
  const float* w2 = (const float*)d_in[2];
  const float* w3 = (const float*)d_in[3];
  float* out = (float*)d_out;

  // bf16 x lives in the first 128 MB of d_out (d_out is 256 MB fp32; validated only
  // after the launch completes, and GEMM2's writes happen after all xb reads).
  bf16_t* xb = (bf16_t*)d_out;
  char* ws = (char*)d_ws;
  const long MB = 1024L * 1024L;

  {
    long n4 = (long)E_ * T_ * D_ / 4;
    cvt_f32_bf16<<<dim3((unsigned)((n4 + 255) / 256)), dim3(256), 0, stream>>>(x, xb, n4);
  }

  const long sWfull = (long)D_ * HDIM;  // per-expert weight elems (all three weights)
  if (ws_size >= (size_t)(160 * MB)) {
    // full-batch path
    bf16_t* w1t = (bf16_t*)(ws + 0 * MB);
    bf16_t* w3t = (bf16_t*)(ws + 32 * MB);
    bf16_t* w2t = (bf16_t*)(ws + 64 * MB);
    bf16_t* hbuf = (bf16_t*)(ws + 96 * MB);

    transpose_cvt<<<dim3(HDIM / 32, D_ / 32, E_), 256, 0, stream>>>(w1, w1t, D_, HDIM, sWfull, sWfull);
    transpose_cvt<<<dim3(HDIM / 32, D_ / 32, E_), 256, 0, stream>>>(w3, w3t, D_, HDIM, sWfull, sWfull);
    transpose_cvt<<<dim3(D_ / 32, HDIM / 32, E_), 256, 0, stream>>>(w2, w2t, HDIM, D_, sWfull, sWfull);

    gemm1_silu<<<dim3(HDIM / 128, T_ / 256, E_), 512, 0, stream>>>(
        xb, w1t, w3t, hbuf, (long)T_ * D_, sWfull, (long)T_ * HDIM);
    gemm2<<<dim3(D_ / 256, T_ / 256, E_), 512, 0, stream>>>(
        hbuf, w2t, out, (long)T_ * HDIM, sWfull, (long)T_ * D_);
  } else {
    // chunked per-expert path (needs only 20 MB of ws). Reverse expert order so that
    // gemm2(e)'s fp32 writes into d_out (clobbering xb[2e],xb[2e+1]) only touch
    // xb slabs whose gemm1 already ran.
    bf16_t* w1t = (bf16_t*)(ws + 0 * MB);
    bf16_t* w3t = (bf16_t*)(ws + 4 * MB);
    bf16_t* w2t = (bf16_t*)(ws + 8 * MB);
    bf16_t* hbuf = (bf16_t*)(ws + 12 * MB);
    for (int e = E_ - 1; e >= 0; --e) {
      const float* w1e = w1 + (long)e * sWfull;
      const float* w3e = w3 + (long)e * sWfull;
      const float* w2e = w2 + (long)e * sWfull;
      transpose_cvt<<<dim3(HDIM / 32, D_ / 32, 1), 256, 0, stream>>>(w1e, w1t, D_, HDIM, 0, 0);
      transpose_cvt<<<dim3(HDIM / 32, D_ / 32, 1), 256, 0, stream>>>(w3e, w3t, D_, HDIM, 0, 0);
      transpose_cvt<<<dim3(D_ / 32, HDIM / 32, 1), 256, 0, stream>>>(w2e, w2t, HDIM, D_, 0, 0);
      gemm1_silu<<<dim3(HDIM / 128, T_ / 256, 1), 512, 0, stream>>>(
          xb + (long)e * T_ * D_, w1t, w3t, hbuf, 0, 0, 0);
      gemm2<<<dim3(D_ / 256, T_ / 256, 1), 512, 0, stream>>>(
          hbuf, w2t, out + (long)e * T_ * D_, 0, 0, 0);
    }
  }
}